// Round 6
// baseline (187.885 us; speedup 1.0000x reference)
//
#include <hip/hip_runtime.h>
#include <cstdint>
#include <cstddef>

#define DEV __device__ __forceinline__

typedef float  f32x4  __attribute__((ext_vector_type(4)));
typedef __bf16 bf16x4 __attribute__((ext_vector_type(4)));
typedef __bf16 bf16x8 __attribute__((ext_vector_type(8)));

constexpr int B = 8, S = 2048, E = 1024, D = 128;
constexpr int M = B * S; // 16384

// ws layout (shorts): q[M][D] | k[M][D] | v_t[D][M] | Wbf[384][E]
constexpr size_t WS_QKV   = (size_t)3 * M * D;
constexpr size_t WS_NEED  = (WS_QKV + (size_t)3 * D * E) * 2; // bytes

// bf16 vs fp32 sniff (wave-uniform, deterministic)
DEV int sniff_is_bf16(const uint32_t* w) {
  int lane = threadIdx.x & 63;
  uint32_t v = w[lane * 1001];
  int e = (v >> 7) & 0xff;
  unsigned long long b = __ballot(e >= 100 && e <= 140);
  return __popcll(b) >= 48;
}

DEV bf16x4 cvt4(float4 f) {
  bf16x4 r; r[0] = (__bf16)f.x; r[1] = (__bf16)f.y; r[2] = (__bf16)f.z; r[3] = (__bf16)f.w;
  return r;
}

// global->LDS direct DMA, 16B/lane. LDS dest = wave-uniform base + lane*16.
DEV void glds16(const void* g, void* l) {
  __builtin_amdgcn_global_load_lds(
      (const __attribute__((address_space(1))) void*)g,
      (__attribute__((address_space(3))) void*)l, 16, 0, 0);
}

// ---------------------------------------------------------------------------
// Kernel 0: cast W (q|k|v stacked, 384 rows x 1024) to bf16 once.
// ---------------------------------------------------------------------------
__global__ __launch_bounds__(256) void wcast_kernel(
    const void* __restrict__ xp, const void* __restrict__ wqp,
    const void* __restrict__ wkp, const void* __restrict__ wvp,
    unsigned short* __restrict__ wbf) {
  const int is_b = sniff_is_bf16((const uint32_t*)xp);
  const int row = blockIdx.x; // 0..383
  const void* src = row < 128 ? wqp : (row < 256 ? wkp : wvp);
  const int r = row & 127;
  const int t = threadIdx.x;
  if (is_b) {
    const uint2* s = (const uint2*)((const unsigned short*)src + (size_t)r * E) + t;
    *((uint2*)(wbf + (size_t)row * E) + t) = *s;
  } else {
    float4 f = *((const float4*)((const float*)src + (size_t)r * E) + t);
    *((bf16x4*)(wbf + (size_t)row * E) + t) = cvt4(f);
  }
}

// ---------------------------------------------------------------------------
// Kernel 1: fused QKV projection. 32-row tiles, grid 512, 2 blocks/CU.
// Wave layout 2 row-groups x 4 col-groups (rg=w>>2, cg=w&3), acc[6].
// (unchanged from r5 — passed at absmax 0.0156)
// ---------------------------------------------------------------------------
__global__ __launch_bounds__(512, 4) void proj_kernel(
    const void* __restrict__ xp, const void* __restrict__ wqp,
    const void* __restrict__ wkp, const void* __restrict__ wvp,
    const unsigned short* __restrict__ wbf, const int use_wbf,
    unsigned short* __restrict__ ws) {
  __shared__ __align__(16) unsigned short lds[(32 + 384) * 72];
  unsigned short* xbuf = lds;
  unsigned short* wbuf = lds + 32 * 72;

  const int is_b = sniff_is_bf16((const uint32_t*)xp);
  const int m0 = blockIdx.x * 32;

  const int t = threadIdx.x, lane = t & 63, w = t >> 6;
  const int n15 = lane & 15, quad = lane >> 4;
  const int rg = w >> 2, cg = w & 3; // wave tile: rows rg*16, cols cg*96

  f32x4 acc[6] = {};
  const int sr = t >> 3, sc8 = (t & 7) * 8; // x-stage: threads <256 cover 32 rows
  const int wr = t >> 3;                    // w-stage: 64 rows per j-group

  for (int it = 0; it < 16; ++it) {
    const int k0 = it * 64;
    __syncthreads();
    // x slab (32 rows x 64 cols)
    if (t < 256) {
      if (!is_b) {
        const float4* sx = (const float4*)((const float*)xp + (size_t)(m0 + sr) * E + k0 + sc8);
        *(bf16x4*)&xbuf[sr * 72 + sc8] = cvt4(sx[0]);
        *(bf16x4*)&xbuf[sr * 72 + sc8 + 4] = cvt4(sx[1]);
      } else {
        *(uint4*)&xbuf[sr * 72 + sc8] =
            *(const uint4*)((const unsigned short*)xp + (size_t)(m0 + sr) * E + k0 + sc8);
      }
    }
    // W slab (384 x 64)
    if (use_wbf) {
#pragma unroll
      for (int j = 0; j < 6; ++j)
        *(uint4*)&wbuf[(j * 64 + wr) * 72 + sc8] =
            *(const uint4*)(wbf + (size_t)(j * 64 + wr) * E + k0 + sc8);
    } else if (!is_b) {
#pragma unroll
      for (int j = 0; j < 6; ++j) {
        const float* wsrc = (j < 2) ? (const float*)wqp : (j < 4) ? (const float*)wkp : (const float*)wvp;
        const int wrow = (j & 1) * 64 + wr;
        const float4* sw = (const float4*)(wsrc + (size_t)wrow * E + k0 + sc8);
        *(bf16x4*)&wbuf[(j * 64 + wr) * 72 + sc8] = cvt4(sw[0]);
        *(bf16x4*)&wbuf[(j * 64 + wr) * 72 + sc8 + 4] = cvt4(sw[1]);
      }
    } else {
#pragma unroll
      for (int j = 0; j < 6; ++j) {
        const unsigned short* wsrc = (j < 2) ? (const unsigned short*)wqp
                                   : (j < 4) ? (const unsigned short*)wkp
                                             : (const unsigned short*)wvp;
        const int wrow = (j & 1) * 64 + wr;
        *(uint4*)&wbuf[(j * 64 + wr) * 72 + sc8] =
            *(const uint4*)(wsrc + (size_t)wrow * E + k0 + sc8);
      }
    }
    __syncthreads();
#pragma unroll
    for (int ks = 0; ks < 2; ++ks) {
      bf16x8 a = *(const bf16x8*)&xbuf[(rg * 16 + n15) * 72 + ks * 32 + quad * 8];
#pragma unroll
      for (int nf = 0; nf < 6; ++nf) {
        bf16x8 bfr = *(const bf16x8*)&wbuf[(cg * 96 + nf * 16 + n15) * 72 + ks * 32 + quad * 8];
        acc[nf] = __builtin_amdgcn_mfma_f32_16x16x32_bf16(a, bfr, acc[nf], 0, 0, 0);
      }
    }
  }

  unsigned short* qws = ws;
  unsigned short* kws = ws + (size_t)M * D;
  unsigned short* vtw = ws + (size_t)2 * M * D;

  __syncthreads();
  unsigned short* tbuf = lds; // [32][132]
#pragma unroll
  for (int nf = 0; nf < 6; ++nf) {
    const int col = cg * 96 + nf * 16 + n15; // 0..383
    const int self = col >> 7;               // 0=q 1=k 2=v
    if (self < 2) {
      unsigned short* dst = self ? kws : qws;
      const int gcol = col & 127;
#pragma unroll
      for (int rr = 0; rr < 4; ++rr) {
        const int grow = m0 + rg * 16 + quad * 4 + rr;
        ((__bf16*)dst)[(size_t)grow * D + gcol] = (__bf16)acc[nf][rr];
      }
    } else {
      const int vcol = col - 256;
#pragma unroll
      for (int rr = 0; rr < 4; ++rr)
        ((__bf16*)tbuf)[(rg * 16 + quad * 4 + rr) * 132 + vcol] = (__bf16)acc[nf][rr];
    }
  }
  __syncthreads();
  {
    const int dcol = t >> 2, mst = (t & 3) * 8;
    unsigned short tmp[8] __attribute__((aligned(16)));
#pragma unroll
    for (int j = 0; j < 8; ++j) tmp[j] = tbuf[(mst + j) * 132 + dcol];
    *(uint4*)&vtw[(size_t)dcol * M + m0 + mst] = *(const uint4*)&tmp[0];
  }
}

// ---------------------------------------------------------------------------
// Kernel 2: causal attention. r5 post-mortem: big+small block pairing gave
// 1 resident block (4 waves/CU) for 94% of the makespan -> 3400cy/chunk vs
// ~1000 modeled. Fix: 8 waves INSIDE one block (512 thr) = 2 q-rowgroups x
// 4 key-quarters; chunk = 128 keys (K 32KB + V 32KB, dbuf 128KB+P ~141KB ->
// 1 block/CU by construction, 8 waves/CU = 2/SIMD guaranteed). Per-wave
// per-chunk work identical to r5 (32 keys), chunks halve. Counted vmcnt(8)
// prefetch spanning barriers kept. Grid 512 = one 32-row q-tile per block,
// DESCENDING size order (LPT under greedy dispatch; 17 chunk-iters/CU avg).
// ---------------------------------------------------------------------------
__global__ __launch_bounds__(512, 2) void attn_kernel(
    const void* __restrict__ xp, const unsigned short* __restrict__ ws,
    void* __restrict__ outp) {
  __shared__ __align__(16) unsigned short kvbuf[2 * 32768]; // 2 x (K 32KB | V 32KB)
  __shared__ __align__(16) unsigned short ldsP[8 * 640];    // 8 waves x [16][40]
  __shared__ float lbuf[32];
  __shared__ int cnt2[2];

  const int is_b = sniff_is_bf16((const uint32_t*)xp);
  const int bx = blockIdx.x;
  const int batch = bx & 7;
  const int t16 = 63 - (bx >> 3); // descending tile size (LPT)
  const int q0 = t16 * 32;
  const int t = threadIdx.x, lane = t & 63, s = t >> 6; // s: 0..7
  const int qg = s >> 2, kq = s & 3;                    // q-rowgroup, key-quarter
  const int n15 = lane & 15, quad = lane >> 4;

  const unsigned short* qws = ws;
  const unsigned short* kws = ws + (size_t)M * D;
  const unsigned short* vtw = ws + (size_t)2 * M * D;
  unsigned short* ldsPw = ldsP + s * 640;

  if (t < 2) cnt2[t] = 0;

  // Q fragments (B-operand) for this wave's 16 rows: lane n15 = q-row
  bf16x8 qf[4];
  {
    const size_t qbase = (size_t)(batch * S + q0 + qg * 16 + n15) * D;
#pragma unroll
    for (int ks = 0; ks < 4; ++ks)
      qf[ks] = *(const bf16x8*)&qws[qbase + ks * 32 + quad * 8];
  }

  const bf16x8 ones = {(__bf16)1.0f, (__bf16)1.0f, (__bf16)1.0f, (__bf16)1.0f,
                       (__bf16)1.0f, (__bf16)1.0f, (__bf16)1.0f, (__bf16)1.0f};

  f32x4 o[8] = {};
  f32x4 lacc = {};

  const int nch = (q0 + 159) >> 7;           // 128-key chunks covering 0..q0+31
  const int wrow = q0 + qg * 16 + 15;        // wave's last q-row
  const int ncw = (wrow >= kq * 32) ? (((wrow - kq * 32) >> 7) + 1) : 0;

  const int r4 = lane >> 4, c16 = lane & 15; // staging lane decomposition (rows 256B)
  const size_t kgbase = (size_t)(batch * S) * D;
  const size_t vgbase = (size_t)batch * S;

  // stage 128-key chunk at key j0c into buffer b: per wave 4 K + 4 V glds16.
  // K rows (128) and V d-rows (128) are both 256B; LDS linear, global source
  // column pre-swizzled (rule 21: dest linear + inv-swz src + swz read).
#define STAGE(j0c, b)                                                              \
  {                                                                                \
    unsigned short* kb_ = kvbuf + (b)*32768;                                       \
    unsigned short* vb_ = kb_ + 16384;                                             \
    _Pragma("unroll") for (int j = 0; j < 4; ++j) {                                \
      const int krow = s * 16 + j * 4 + r4; /* local key 0..127 */                 \
      glds16(kws + kgbase + (size_t)((j0c) + krow) * D + ((c16 ^ (krow & 7)) << 3), \
             kb_ + (s * 16 + j * 4) * 128);                                        \
    }                                                                              \
    _Pragma("unroll") for (int j = 0; j < 4; ++j) {                                \
      const int dr = s * 16 + j * 4 + r4; /* d-row 0..127 */                       \
      glds16(vtw + (size_t)dr * M + vgbase + (j0c) + ((c16 ^ (dr & 7)) << 3),      \
             vb_ + (s * 16 + j * 4) * 128);                                        \
    }                                                                              \
  }

  STAGE(0, 0);

  for (int c = 0; c < nch; ++c) {
    if (c + 1 < nch) {
      STAGE((c + 1) * 128, (c + 1) & 1);
      // drain chunk c's 8 glds16 (oldest); keep c+1's 8 in flight
      asm volatile("s_waitcnt vmcnt(8)" ::: "memory");
    } else {
      asm volatile("s_waitcnt vmcnt(0)" ::: "memory");
    }
    __builtin_amdgcn_s_barrier(); // chunk c fully in LDS for all waves

    if (c < ncw) {
      const unsigned short* kb = kvbuf + (c & 1) * 32768;
      const unsigned short* vb = kb + 16384;
      const int xsw = n15 & 7;

      // S^T = K Q^T : col = q-row (n15), row = key (quad*4+rr)
      f32x4 sc[2] = {};
      __builtin_amdgcn_s_setprio(1);
#pragma unroll
      for (int nt = 0; nt < 2; ++nt) {
        const int klrow = kq * 32 + nt * 16 + n15;
#pragma unroll
        for (int ks = 0; ks < 4; ++ks) {
          const bf16x8 ka = *(const bf16x8*)&kb[klrow * 128 + (((ks * 4 + quad) ^ xsw) << 3)];
          sc[nt] = __builtin_amdgcn_mfma_f32_16x16x32_bf16(ka, qf[ks], sc[nt], 0, 0, 0);
        }
      }
      __builtin_amdgcn_s_setprio(0);

      // softmax: fixed-max exp(score/128); mask only on the wave's last chunk
      const int j0 = c * 128 + kq * 32;
      const bool maskc = (c == ncw - 1);
#pragma unroll
      for (int nt = 0; nt < 2; ++nt) {
        bf16x4 pv;
#pragma unroll
        for (int rr = 0; rr < 4; ++rr) {
          float v = sc[nt][rr] * (1.0f / 128.0f);
          if (maskc && (j0 + nt * 16 + quad * 4 + rr > q0 + qg * 16 + n15)) v = -1e30f;
          pv[rr] = (__bf16)__expf(v);
        }
        *(bf16x4*)&ldsPw[n15 * 40 + nt * 16 + quad * 4] = pv;
      }

      // PV (same-wave LDS write->read, lgkmcnt-ordered by compiler)
      const bf16x8 pa = *(const bf16x8*)&ldsPw[n15 * 40 + quad * 8];
      __builtin_amdgcn_s_setprio(1);
#pragma unroll
      for (int dn = 0; dn < 8; ++dn) {
        const bf16x8 vfr =
            *(const bf16x8*)&vb[(dn * 16 + n15) * 128 + (((kq * 4 + quad) ^ xsw) << 3)];
        o[dn] = __builtin_amdgcn_mfma_f32_16x16x32_bf16(pa, vfr, o[dn], 0, 0, 0);
      }
      lacc = __builtin_amdgcn_mfma_f32_16x16x32_bf16(pa, ones, lacc, 0, 0, 0);
      __builtin_amdgcn_s_setprio(0);
    }

    __builtin_amdgcn_s_barrier(); // all reads of buf[c&1] done before reuse
  }

  __syncthreads(); // full drain; enables Obuf overlay on kvbuf

  // merge per q-rowgroup: kq==0 wave stores, kq 1-3 ds_add after arrival
  float* Obuf = (float*)kvbuf; // [32][132]
  if (kq == 0) {
#pragma unroll
    for (int dn = 0; dn < 8; ++dn)
#pragma unroll
      for (int rr = 0; rr < 4; ++rr)
        Obuf[(qg * 16 + quad * 4 + rr) * 132 + dn * 16 + n15] = o[dn][rr];
    if (n15 == 0)
#pragma unroll
      for (int rr = 0; rr < 4; ++rr)
        lbuf[qg * 16 + quad * 4 + rr] = lacc[rr];
    asm volatile("" ::: "memory");
    if (lane == 0) atomicAdd(&cnt2[qg], 1);
  } else {
    while (__hip_atomic_load(&cnt2[qg], __ATOMIC_RELAXED, __HIP_MEMORY_SCOPE_WORKGROUP) < 1)
      __builtin_amdgcn_s_sleep(1);
    asm volatile("" ::: "memory");
#pragma unroll
    for (int dn = 0; dn < 8; ++dn)
#pragma unroll
      for (int rr = 0; rr < 4; ++rr)
        atomicAdd(&Obuf[(qg * 16 + quad * 4 + rr) * 132 + dn * 16 + n15], o[dn][rr]);
    if (n15 == 0)
#pragma unroll
      for (int rr = 0; rr < 4; ++rr)
        atomicAdd(&lbuf[qg * 16 + quad * 4 + rr], lacc[rr]);
    if (lane == 0) atomicAdd(&cnt2[qg], 1);
  }
  while (__hip_atomic_load(&cnt2[0], __ATOMIC_RELAXED, __HIP_MEMORY_SCOPE_WORKGROUP) < 4 ||
         __hip_atomic_load(&cnt2[1], __ATOMIC_RELAXED, __HIP_MEMORY_SCOPE_WORKGROUP) < 4)
    __builtin_amdgcn_s_sleep(1);
  asm volatile("" ::: "memory");

  // cooperative epilogue: 32 rows x 128 cols over 512 threads
  {
    const int row = t >> 4, cb = (t & 15) * 8;
    const float invl = 1.0f / lbuf[row];
    const size_t grow = (size_t)(batch * S + q0 + row) * D;
    if (is_b) {
#pragma unroll
      for (int i = 0; i < 8; ++i)
        ((__bf16*)outp)[grow + cb + i] = (__bf16)(Obuf[row * 132 + cb + i] * invl);
    } else {
#pragma unroll
      for (int i = 0; i < 8; ++i)
        ((float*)outp)[grow + cb + i] = Obuf[row * 132 + cb + i] * invl;
    }
  }
#undef STAGE
}

extern "C" void kernel_launch(void* const* d_in, const int* in_sizes, int n_in,
                              void* d_out, int out_size, void* d_ws, size_t ws_size,
                              hipStream_t stream) {
  (void)in_sizes; (void)n_in; (void)out_size;
  const void* x  = d_in[0];
  const void* wq = d_in[1];
  const void* wk = d_in[2];
  const void* wv = d_in[3];
  unsigned short* ws = (unsigned short*)d_ws;
  unsigned short* wbf = ws + WS_QKV;
  const int use_wbf = (ws_size >= WS_NEED) ? 1 : 0;

  if (use_wbf)
    wcast_kernel<<<dim3(384), dim3(256), 0, stream>>>(x, wq, wk, wv, wbf);
  proj_kernel<<<dim3(512), dim3(512), 0, stream>>>(x, wq, wk, wv, wbf, use_wbf, ws);
  attn_kernel<<<dim3(512), dim3(512), 0, stream>>>(x, ws, d_out);
}

// Round 7
// 174.820 us; speedup vs baseline: 1.0747x; 1.0747x over previous
//
#include <hip/hip_runtime.h>
#include <cstdint>
#include <cstddef>

#define DEV __device__ __forceinline__

typedef float  f32x4  __attribute__((ext_vector_type(4)));
typedef __bf16 bf16x4 __attribute__((ext_vector_type(4)));
typedef __bf16 bf16x8 __attribute__((ext_vector_type(8)));

constexpr int B = 8, S = 2048, E = 1024, D = 128;
constexpr int M = B * S; // 16384

// ws layout (shorts): q[M][D] | k[M][D] | v_t[D][M] | Wbf[384][E] | f32: ws2[M][D] | lws[M]
constexpr size_t WS_QKV    = (size_t)3 * M * D;
constexpr size_t WS_F32OFF = WS_QKV + (size_t)3 * D * E;            // shorts
constexpr size_t WS_NEED   = WS_F32OFF * 2;                         // bytes (wbf path)
constexpr size_t WS_NEED2  = WS_F32OFF * 2 + ((size_t)M * D + M) * 4; // bytes (split-K path)
constexpr int    NZ4       = (M * D + M) / 4;                       // float4s to zero

// bf16 vs fp32 sniff (wave-uniform, deterministic)
DEV int sniff_is_bf16(const uint32_t* w) {
  int lane = threadIdx.x & 63;
  uint32_t v = w[lane * 1001];
  int e = (v >> 7) & 0xff;
  unsigned long long b = __ballot(e >= 100 && e <= 140);
  return __popcll(b) >= 48;
}

DEV bf16x4 cvt4(float4 f) {
  bf16x4 r; r[0] = (__bf16)f.x; r[1] = (__bf16)f.y; r[2] = (__bf16)f.z; r[3] = (__bf16)f.w;
  return r;
}

// global->LDS direct DMA, 16B/lane. LDS dest = wave-uniform base + lane*16.
DEV void glds16(const void* g, void* l) {
  __builtin_amdgcn_global_load_lds(
      (const __attribute__((address_space(1))) void*)g,
      (__attribute__((address_space(3))) void*)l, 16, 0, 0);
}

// ---------------------------------------------------------------------------
// Kernel 0: cast W (q|k|v stacked, 384 rows x 1024) to bf16 once; fused
// grid-stride zeroing of the f32 accumulator region (split-K path).
// ---------------------------------------------------------------------------
__global__ __launch_bounds__(256) void wcast_kernel(
    const void* __restrict__ xp, const void* __restrict__ wqp,
    const void* __restrict__ wkp, const void* __restrict__ wvp,
    unsigned short* __restrict__ wbf, float* __restrict__ zbuf, const int nz4) {
  const int is_b = sniff_is_bf16((const uint32_t*)xp);
  const int row = blockIdx.x; // 0..383
  const void* src = row < 128 ? wqp : (row < 256 ? wkp : wvp);
  const int r = row & 127;
  const int t = threadIdx.x;
  if (is_b) {
    const uint2* s = (const uint2*)((const unsigned short*)src + (size_t)r * E) + t;
    *((uint2*)(wbf + (size_t)row * E) + t) = *s;
  } else {
    float4 f = *((const float4*)((const float*)src + (size_t)r * E) + t);
    *((bf16x4*)(wbf + (size_t)row * E) + t) = cvt4(f);
  }
  if (nz4) {
    float4 z = {0.f, 0.f, 0.f, 0.f};
    float4* zp = (float4*)zbuf;
    for (int i = blockIdx.x * 256 + t; i < nz4; i += 384 * 256) zp[i] = z;
  }
}

// ---------------------------------------------------------------------------
// Kernel 1: fused QKV projection. 32-row tiles, grid 512, 2 blocks/CU.
// Wave layout 2 row-groups x 4 col-groups (rg=w>>2, cg=w&3), acc[6].
// (unchanged from r5 — passed at absmax 0.0156)
// ---------------------------------------------------------------------------
__global__ __launch_bounds__(512, 4) void proj_kernel(
    const void* __restrict__ xp, const void* __restrict__ wqp,
    const void* __restrict__ wkp, const void* __restrict__ wvp,
    const unsigned short* __restrict__ wbf, const int use_wbf,
    unsigned short* __restrict__ ws) {
  __shared__ __align__(16) unsigned short lds[(32 + 384) * 72];
  unsigned short* xbuf = lds;
  unsigned short* wbuf = lds + 32 * 72;

  const int is_b = sniff_is_bf16((const uint32_t*)xp);
  const int m0 = blockIdx.x * 32;

  const int t = threadIdx.x, lane = t & 63, w = t >> 6;
  const int n15 = lane & 15, quad = lane >> 4;
  const int rg = w >> 2, cg = w & 3; // wave tile: rows rg*16, cols cg*96

  f32x4 acc[6] = {};
  const int sr = t >> 3, sc8 = (t & 7) * 8;
  const int wr = t >> 3;

  for (int it = 0; it < 16; ++it) {
    const int k0 = it * 64;
    __syncthreads();
    if (t < 256) {
      if (!is_b) {
        const float4* sx = (const float4*)((const float*)xp + (size_t)(m0 + sr) * E + k0 + sc8);
        *(bf16x4*)&xbuf[sr * 72 + sc8] = cvt4(sx[0]);
        *(bf16x4*)&xbuf[sr * 72 + sc8 + 4] = cvt4(sx[1]);
      } else {
        *(uint4*)&xbuf[sr * 72 + sc8] =
            *(const uint4*)((const unsigned short*)xp + (size_t)(m0 + sr) * E + k0 + sc8);
      }
    }
    if (use_wbf) {
#pragma unroll
      for (int j = 0; j < 6; ++j)
        *(uint4*)&wbuf[(j * 64 + wr) * 72 + sc8] =
            *(const uint4*)(wbf + (size_t)(j * 64 + wr) * E + k0 + sc8);
    } else if (!is_b) {
#pragma unroll
      for (int j = 0; j < 6; ++j) {
        const float* wsrc = (j < 2) ? (const float*)wqp : (j < 4) ? (const float*)wkp : (const float*)wvp;
        const int wrow = (j & 1) * 64 + wr;
        const float4* sw = (const float4*)(wsrc + (size_t)wrow * E + k0 + sc8);
        *(bf16x4*)&wbuf[(j * 64 + wr) * 72 + sc8] = cvt4(sw[0]);
        *(bf16x4*)&wbuf[(j * 64 + wr) * 72 + sc8 + 4] = cvt4(sw[1]);
      }
    } else {
#pragma unroll
      for (int j = 0; j < 6; ++j) {
        const unsigned short* wsrc = (j < 2) ? (const unsigned short*)wqp
                                   : (j < 4) ? (const unsigned short*)wkp
                                             : (const unsigned short*)wvp;
        const int wrow = (j & 1) * 64 + wr;
        *(uint4*)&wbuf[(j * 64 + wr) * 72 + sc8] =
            *(const uint4*)(wsrc + (size_t)wrow * E + k0 + sc8);
      }
    }
    __syncthreads();
#pragma unroll
    for (int ks = 0; ks < 2; ++ks) {
      bf16x8 a = *(const bf16x8*)&xbuf[(rg * 16 + n15) * 72 + ks * 32 + quad * 8];
#pragma unroll
      for (int nf = 0; nf < 6; ++nf) {
        bf16x8 bfr = *(const bf16x8*)&wbuf[(cg * 96 + nf * 16 + n15) * 72 + ks * 32 + quad * 8];
        acc[nf] = __builtin_amdgcn_mfma_f32_16x16x32_bf16(a, bfr, acc[nf], 0, 0, 0);
      }
    }
  }

  unsigned short* qws = ws;
  unsigned short* kws = ws + (size_t)M * D;
  unsigned short* vtw = ws + (size_t)2 * M * D;

  __syncthreads();
  unsigned short* tbuf = lds; // [32][132]
#pragma unroll
  for (int nf = 0; nf < 6; ++nf) {
    const int col = cg * 96 + nf * 16 + n15;
    const int self = col >> 7;
    if (self < 2) {
      unsigned short* dst = self ? kws : qws;
      const int gcol = col & 127;
#pragma unroll
      for (int rr = 0; rr < 4; ++rr) {
        const int grow = m0 + rg * 16 + quad * 4 + rr;
        ((__bf16*)dst)[(size_t)grow * D + gcol] = (__bf16)acc[nf][rr];
      }
    } else {
      const int vcol = col - 256;
#pragma unroll
      for (int rr = 0; rr < 4; ++rr)
        ((__bf16*)tbuf)[(rg * 16 + quad * 4 + rr) * 132 + vcol] = (__bf16)acc[nf][rr];
    }
  }
  __syncthreads();
  {
    const int dcol = t >> 2, mst = (t & 3) * 8;
    unsigned short tmp[8] __attribute__((aligned(16)));
#pragma unroll
    for (int j = 0; j < 8; ++j) tmp[j] = tbuf[(mst + j) * 132 + dcol];
    *(uint4*)&vtw[(size_t)dcol * M + m0 + mst] = *(const uint4*)&tmp[0];
  }
}

// ---------------------------------------------------------------------------
// Kernel 2a (primary): split-K segmented attention. r6 post-mortem: one-tile-
// per-block can NEVER balance (all 512 blocks resident at once -> need equal
// pair-sums AND equal members; sizes 1..33). Fix: r5's 4-wave/64-key engine
// verbatim, but each 32-row tile is split into 2 key segments -> 1024 blocks
// of <=17 chunks, both segments of a tile adjacent, descending size (first
// 512 resident blocks are sizes ~16..9 -> balanced; refill fills the tail).
// Fixed-max softmax makes segment partials exactly additive: each block
// atomicAdds unnormalized O (f32) + l into ws2/lws; finalize divides. This
// also deletes the LDS merge/polling (LDS 69KB -> 2 blocks/CU).
// ---------------------------------------------------------------------------
__global__ __launch_bounds__(256, 2) void attn_seg_kernel(
    const unsigned short* __restrict__ ws, float* __restrict__ ws2,
    float* __restrict__ lws) {
  __shared__ __align__(16) unsigned short kvbuf[2 * 16384]; // 2 x (K 16KB | V 16KB)
  __shared__ __align__(16) unsigned short ldsP[4 * 640];    // 4 waves x [16][40]

  const int bx = blockIdx.x;
  const int batch = bx & 7;
  const int seg = (bx >> 3) & 1;
  const int t16 = 63 - (bx >> 4); // descending tile size, both segs adjacent
  const int q0 = t16 * 32;

  const int nch = (q0 + 95) >> 6;          // global 64-key chunk count for tile
  const int c0 = seg ? ((nch + 1) >> 1) : 0;
  const int c1 = seg ? nch : ((nch + 1) >> 1);
  if (c0 >= c1) return;                    // empty segment (tiny tiles)

  const int t = threadIdx.x, lane = t & 63, s = t >> 6;
  const int qg = s >> 1, kh = s & 1;       // q-rowgroup, key-half
  const int n15 = lane & 15, quad = lane >> 4;

  const unsigned short* qws = ws;
  const unsigned short* kws = ws + (size_t)M * D;
  const unsigned short* vtw = ws + (size_t)2 * M * D;
  unsigned short* ldsPw = ldsP + s * 640;

  // Q fragments (B-operand) for this wave's 16 rows: lane n15 = q-row
  bf16x8 qf[4];
  {
    const size_t qbase = (size_t)(batch * S + q0 + qg * 16 + n15) * D;
#pragma unroll
    for (int ks = 0; ks < 4; ++ks)
      qf[ks] = *(const bf16x8*)&qws[qbase + ks * 32 + quad * 8];
  }

  const bf16x8 ones = {(__bf16)1.0f, (__bf16)1.0f, (__bf16)1.0f, (__bf16)1.0f,
                       (__bf16)1.0f, (__bf16)1.0f, (__bf16)1.0f, (__bf16)1.0f};

  f32x4 o[8] = {};
  f32x4 lacc = {};

  const int wrow = q0 + qg * 16 + 15;      // wave's last q-row
  const int ncw = (wrow >= kh * 32) ? (((wrow - kh * 32) >> 6) + 1) : 0; // global

  const int r4 = lane >> 4, c16 = lane & 15;
  const int r8 = lane >> 3, c8 = lane & 7;
  const size_t kgbase = (size_t)(batch * S) * D;
  const size_t vgbase = (size_t)batch * S;

#define STAGE(j0c, b)                                                            \
  {                                                                              \
    unsigned short* kb_ = kvbuf + (b)*16384;                                     \
    unsigned short* vb_ = kb_ + 8192;                                            \
    _Pragma("unroll") for (int j = 0; j < 4; ++j) {                              \
      const int krow = s * 16 + j * 4 + r4;                                      \
      glds16(kws + kgbase + (size_t)((j0c) + krow) * D + ((c16 ^ (krow & 7)) << 3), \
             kb_ + (s * 16 + j * 4) * 128);                                      \
    }                                                                            \
    _Pragma("unroll") for (int j = 0; j < 4; ++j) {                              \
      const int dr = s * 32 + j * 8 + r8;                                        \
      glds16(vtw + (size_t)dr * M + vgbase + (j0c) + ((c8 ^ (dr & 7)) << 3),     \
             vb_ + (s * 32 + j * 8) * 64);                                       \
    }                                                                            \
  }

  STAGE(c0 * 64, c0 & 1);

  for (int c = c0; c < c1; ++c) {
    if (c + 1 < c1) {
      STAGE((c + 1) * 64, (c + 1) & 1);
      asm volatile("s_waitcnt vmcnt(8)" ::: "memory"); // drain chunk c only
    } else {
      asm volatile("s_waitcnt vmcnt(0)" ::: "memory");
    }
    __builtin_amdgcn_s_barrier();

    if (c < ncw) {
      const unsigned short* kb = kvbuf + (c & 1) * 16384;
      const unsigned short* vb = kb + 8192;
      const int xsw = n15 & 7;

      f32x4 sc[2] = {};
      __builtin_amdgcn_s_setprio(1);
#pragma unroll
      for (int nt = 0; nt < 2; ++nt) {
        const int klrow = kh * 32 + nt * 16 + n15;
#pragma unroll
        for (int ks = 0; ks < 4; ++ks) {
          const bf16x8 ka = *(const bf16x8*)&kb[klrow * 128 + (((ks * 4 + quad) ^ xsw) << 3)];
          sc[nt] = __builtin_amdgcn_mfma_f32_16x16x32_bf16(ka, qf[ks], sc[nt], 0, 0, 0);
        }
      }
      __builtin_amdgcn_s_setprio(0);

      const int j0 = c * 64 + kh * 32;
      const bool maskc = (c == ncw - 1);
#pragma unroll
      for (int nt = 0; nt < 2; ++nt) {
        bf16x4 pv;
#pragma unroll
        for (int rr = 0; rr < 4; ++rr) {
          float v = sc[nt][rr] * (1.0f / 128.0f);
          if (maskc && (j0 + nt * 16 + quad * 4 + rr > q0 + qg * 16 + n15)) v = -1e30f;
          pv[rr] = (__bf16)__expf(v);
        }
        *(bf16x4*)&ldsPw[n15 * 40 + nt * 16 + quad * 4] = pv;
      }

      const bf16x8 pa = *(const bf16x8*)&ldsPw[n15 * 40 + quad * 8];
      __builtin_amdgcn_s_setprio(1);
#pragma unroll
      for (int dn = 0; dn < 8; ++dn) {
        const bf16x8 vfr =
            *(const bf16x8*)&vb[(dn * 16 + n15) * 64 + (((kh * 4 + quad) ^ xsw) << 3)];
        o[dn] = __builtin_amdgcn_mfma_f32_16x16x32_bf16(pa, vfr, o[dn], 0, 0, 0);
      }
      lacc = __builtin_amdgcn_mfma_f32_16x16x32_bf16(pa, ones, lacc, 0, 0, 0);
      __builtin_amdgcn_s_setprio(0);
    }

    __builtin_amdgcn_s_barrier();
  }
#undef STAGE

  // merge: fixed-max partials are exactly additive -> direct f32 atomics
  float* obase = ws2 + (size_t)(batch * S + q0) * D;
#pragma unroll
  for (int dn = 0; dn < 8; ++dn)
#pragma unroll
    for (int rr = 0; rr < 4; ++rr)
      atomicAdd(&obase[(size_t)(qg * 16 + quad * 4 + rr) * D + dn * 16 + n15], o[dn][rr]);
  if (n15 == 0)
#pragma unroll
    for (int rr = 0; rr < 4; ++rr)
      atomicAdd(&lws[batch * S + q0 + qg * 16 + quad * 4 + rr], lacc[rr]);
}

// ---------------------------------------------------------------------------
// Kernel 2b (fallback when ws too small for f32 accumulators): r5 attn
// verbatim (49.7us measured).
// ---------------------------------------------------------------------------
__global__ __launch_bounds__(256, 2) void attn_kernel(
    const void* __restrict__ xp, const unsigned short* __restrict__ ws,
    void* __restrict__ outp) {
  __shared__ __align__(16) unsigned short kvbuf[2 * 16384];
  __shared__ __align__(16) unsigned short ldsP[4 * 640];
  __shared__ float lbuf[32];
  __shared__ int cnt2[2];

  const int is_b = sniff_is_bf16((const uint32_t*)xp);
  const int bx = blockIdx.x;
  const int batch = bx & 7;
  const int g8 = (bx & 255) >> 3;
  const int t16 = (bx < 256) ? (63 - g8) : g8;
  const int q0 = t16 * 32;
  const int t = threadIdx.x, lane = t & 63, s = t >> 6;
  const int qg = s >> 1, kh = s & 1;
  const int n15 = lane & 15, quad = lane >> 4;

  const unsigned short* qws = ws;
  const unsigned short* kws = ws + (size_t)M * D;
  const unsigned short* vtw = ws + (size_t)2 * M * D;
  unsigned short* ldsPw = ldsP + s * 640;

  if (t < 2) cnt2[t] = 0;

  bf16x8 qf[4];
  {
    const size_t qbase = (size_t)(batch * S + q0 + qg * 16 + n15) * D;
#pragma unroll
    for (int ks = 0; ks < 4; ++ks)
      qf[ks] = *(const bf16x8*)&qws[qbase + ks * 32 + quad * 8];
  }

  const bf16x8 ones = {(__bf16)1.0f, (__bf16)1.0f, (__bf16)1.0f, (__bf16)1.0f,
                       (__bf16)1.0f, (__bf16)1.0f, (__bf16)1.0f, (__bf16)1.0f};

  f32x4 o[8] = {};
  f32x4 lacc = {};

  const int nch = (q0 + 95) >> 6;
  const int wrow = q0 + qg * 16 + 15;
  const int ncw = (wrow >= kh * 32) ? (((wrow - kh * 32) >> 6) + 1) : 0;

  const int r4 = lane >> 4, c16 = lane & 15;
  const int r8 = lane >> 3, c8 = lane & 7;
  const size_t kgbase = (size_t)(batch * S) * D;
  const size_t vgbase = (size_t)batch * S;

#define STAGE(j0c, b)                                                            \
  {                                                                              \
    unsigned short* kb_ = kvbuf + (b)*16384;                                     \
    unsigned short* vb_ = kb_ + 8192;                                            \
    _Pragma("unroll") for (int j = 0; j < 4; ++j) {                              \
      const int krow = s * 16 + j * 4 + r4;                                      \
      glds16(kws + kgbase + (size_t)((j0c) + krow) * D + ((c16 ^ (krow & 7)) << 3), \
             kb_ + (s * 16 + j * 4) * 128);                                      \
    }                                                                            \
    _Pragma("unroll") for (int j = 0; j < 4; ++j) {                              \
      const int dr = s * 32 + j * 8 + r8;                                        \
      glds16(vtw + (size_t)dr * M + vgbase + (j0c) + ((c8 ^ (dr & 7)) << 3),     \
             vb_ + (s * 32 + j * 8) * 64);                                       \
    }                                                                            \
  }

  STAGE(0, 0);

  for (int c = 0; c < nch; ++c) {
    if (c + 1 < nch) {
      STAGE((c + 1) * 64, (c + 1) & 1);
      asm volatile("s_waitcnt vmcnt(8)" ::: "memory");
    } else {
      asm volatile("s_waitcnt vmcnt(0)" ::: "memory");
    }
    __builtin_amdgcn_s_barrier();

    if (c < ncw) {
      const unsigned short* kb = kvbuf + (c & 1) * 16384;
      const unsigned short* vb = kb + 8192;
      const int xsw = n15 & 7;

      f32x4 sc[2] = {};
      __builtin_amdgcn_s_setprio(1);
#pragma unroll
      for (int nt = 0; nt < 2; ++nt) {
        const int klrow = kh * 32 + nt * 16 + n15;
#pragma unroll
        for (int ks = 0; ks < 4; ++ks) {
          const bf16x8 ka = *(const bf16x8*)&kb[klrow * 128 + (((ks * 4 + quad) ^ xsw) << 3)];
          sc[nt] = __builtin_amdgcn_mfma_f32_16x16x32_bf16(ka, qf[ks], sc[nt], 0, 0, 0);
        }
      }
      __builtin_amdgcn_s_setprio(0);

      const int j0 = c * 64 + kh * 32;
      const bool maskc = (c == ncw - 1);
#pragma unroll
      for (int nt = 0; nt < 2; ++nt) {
        bf16x4 pv;
#pragma unroll
        for (int rr = 0; rr < 4; ++rr) {
          float v = sc[nt][rr] * (1.0f / 128.0f);
          if (maskc && (j0 + nt * 16 + quad * 4 + rr > q0 + qg * 16 + n15)) v = -1e30f;
          pv[rr] = (__bf16)__expf(v);
        }
        *(bf16x4*)&ldsPw[n15 * 40 + nt * 16 + quad * 4] = pv;
      }

      const bf16x8 pa = *(const bf16x8*)&ldsPw[n15 * 40 + quad * 8];
      __builtin_amdgcn_s_setprio(1);
#pragma unroll
      for (int dn = 0; dn < 8; ++dn) {
        const bf16x8 vfr =
            *(const bf16x8*)&vb[(dn * 16 + n15) * 64 + (((kh * 4 + quad) ^ xsw) << 3)];
        o[dn] = __builtin_amdgcn_mfma_f32_16x16x32_bf16(pa, vfr, o[dn], 0, 0, 0);
      }
      lacc = __builtin_amdgcn_mfma_f32_16x16x32_bf16(pa, ones, lacc, 0, 0, 0);
      __builtin_amdgcn_s_setprio(0);
    }

    __builtin_amdgcn_s_barrier();
  }
#undef STAGE

  __syncthreads();

  float* Obuf = (float*)kvbuf; // [32][132]
  if (kh == 0) {
#pragma unroll
    for (int dn = 0; dn < 8; ++dn)
#pragma unroll
      for (int rr = 0; rr < 4; ++rr)
        Obuf[(qg * 16 + quad * 4 + rr) * 132 + dn * 16 + n15] = o[dn][rr];
    if (n15 == 0)
#pragma unroll
      for (int rr = 0; rr < 4; ++rr)
        lbuf[qg * 16 + quad * 4 + rr] = lacc[rr];
    asm volatile("" ::: "memory");
    if (lane == 0) atomicAdd(&cnt2[qg], 1);
  } else {
    while (__hip_atomic_load(&cnt2[qg], __ATOMIC_RELAXED, __HIP_MEMORY_SCOPE_WORKGROUP) < 1)
      __builtin_amdgcn_s_sleep(1);
    asm volatile("" ::: "memory");
#pragma unroll
    for (int dn = 0; dn < 8; ++dn)
#pragma unroll
      for (int rr = 0; rr < 4; ++rr)
        atomicAdd(&Obuf[(qg * 16 + quad * 4 + rr) * 132 + dn * 16 + n15], o[dn][rr]);
    if (n15 == 0)
#pragma unroll
      for (int rr = 0; rr < 4; ++rr)
        atomicAdd(&lbuf[qg * 16 + quad * 4 + rr], lacc[rr]);
    if (lane == 0) atomicAdd(&cnt2[qg], 1);
  }
  while (__hip_atomic_load(&cnt2[0], __ATOMIC_RELAXED, __HIP_MEMORY_SCOPE_WORKGROUP) < 2 ||
         __hip_atomic_load(&cnt2[1], __ATOMIC_RELAXED, __HIP_MEMORY_SCOPE_WORKGROUP) < 2)
    __builtin_amdgcn_s_sleep(1);
  asm volatile("" ::: "memory");

  {
    const int row = t >> 3, cb = (t & 7) * 16;
    const float invl = 1.0f / lbuf[row];
    const size_t grow = (size_t)(batch * S + q0 + row) * D;
    if (is_b) {
#pragma unroll
      for (int i = 0; i < 16; ++i)
        ((__bf16*)outp)[grow + cb + i] = (__bf16)(Obuf[row * 132 + cb + i] * invl);
    } else {
#pragma unroll
      for (int i = 0; i < 16; ++i)
        ((float*)outp)[grow + cb + i] = Obuf[row * 132 + cb + i] * invl;
    }
  }
}

// ---------------------------------------------------------------------------
// Kernel 3: finalize — out = ws2 / lws, bf16 or f32 output.
// 1024 blocks x 256 thr x 8 elems = M*D exactly.
// ---------------------------------------------------------------------------
__global__ __launch_bounds__(256) void finalize_kernel(
    const void* __restrict__ xp, const float* __restrict__ ws2,
    const float* __restrict__ lws, void* __restrict__ outp) {
  const int is_b = sniff_is_bf16((const uint32_t*)xp);
  const size_t g = ((size_t)blockIdx.x * 256 + threadIdx.x) * 8;
  const int m = (int)(g >> 7);
  const float invl = 1.0f / lws[m];
  float4 a = *(const float4*)(ws2 + g);
  float4 b2 = *(const float4*)(ws2 + g + 4);
  if (is_b) {
    bf16x8 r;
    r[0] = (__bf16)(a.x * invl);  r[1] = (__bf16)(a.y * invl);
    r[2] = (__bf16)(a.z * invl);  r[3] = (__bf16)(a.w * invl);
    r[4] = (__bf16)(b2.x * invl); r[5] = (__bf16)(b2.y * invl);
    r[6] = (__bf16)(b2.z * invl); r[7] = (__bf16)(b2.w * invl);
    *(bf16x8*)((__bf16*)outp + g) = r;
  } else {
    float4 ra = {a.x * invl, a.y * invl, a.z * invl, a.w * invl};
    float4 rb = {b2.x * invl, b2.y * invl, b2.z * invl, b2.w * invl};
    *(float4*)((float*)outp + g) = ra;
    *(float4*)((float*)outp + g + 4) = rb;
  }
}

extern "C" void kernel_launch(void* const* d_in, const int* in_sizes, int n_in,
                              void* d_out, int out_size, void* d_ws, size_t ws_size,
                              hipStream_t stream) {
  (void)in_sizes; (void)n_in; (void)out_size;
  const void* x  = d_in[0];
  const void* wq = d_in[1];
  const void* wk = d_in[2];
  const void* wv = d_in[3];
  unsigned short* ws = (unsigned short*)d_ws;
  unsigned short* wbf = ws + WS_QKV;
  float* ws2 = (float*)(ws + WS_F32OFF);
  float* lws = ws2 + (size_t)M * D;
  const int use_wbf = (ws_size >= WS_NEED) ? 1 : 0;
  const int use_seg = (ws_size >= WS_NEED2) ? 1 : 0;

  if (use_wbf)
    wcast_kernel<<<dim3(384), dim3(256), 0, stream>>>(x, wq, wk, wv, wbf, ws2,
                                                      use_seg ? NZ4 : 0);
  proj_kernel<<<dim3(512), dim3(512), 0, stream>>>(x, wq, wk, wv, wbf, use_wbf, ws);
  if (use_seg) {
    attn_seg_kernel<<<dim3(1024), dim3(256), 0, stream>>>(ws, ws2, lws);
    finalize_kernel<<<dim3(1024), dim3(256), 0, stream>>>(x, ws2, lws, d_out);
  } else {
    attn_kernel<<<dim3(512), dim3(256), 0, stream>>>(x, ws, d_out);
  }
}